// Round 8
// baseline (712.730 us; speedup 1.0000x reference)
//
#include <hip/hip_runtime.h>
#include <hip/hip_bf16.h>
#include <math.h>

typedef __attribute__((ext_vector_type(8)))  _Float16 f16x8;
typedef __attribute__((ext_vector_type(2)))  __fp16   fp16v2;
typedef __attribute__((ext_vector_type(16))) float    f32x16;

// ---------------------------------------------------------------------------
// GATr forward on MI355X. B=4, N=4096, H=5, BLK=3, INV=32, 16 blades.
// Metric (0,1,1,1) PGA. Blade order sorted by (grade, mask).
// Attention: fp16 MFMA, exp2 softmax, K+V register prefetch (depth 1),
// XCD<->batch grid swizzle for L2-resident K/V, 8-way key-split.
// ---------------------------------------------------------------------------

namespace ga {
constexpr int MASKS[16] = {0,1,2,4,8,3,5,6,9,10,12,7,11,13,14,15};
constexpr int popc4(int x){ return (x&1)+((x>>1)&1)+((x>>2)&1)+((x>>3)&1); }
constexpr int idx_of(int m){ int r=-1; for(int i=0;i<16;i++) if(MASKS[i]==m) r=i; return r; }
struct GPTab {
  int cnt[16];
  signed char ii[16][16];
  signed char jj[16][16];
  float ss[16][16];
};
constexpr GPTab make_gptab(){
  GPTab t{};
  for(int i=0;i<16;i++) for(int j=0;j<16;j++){
    int a=MASKS[i], b=MASKS[j];
    if((a&b&1)!=0) continue;           // e0^2 = 0 kills the term
    int sw=0;
    for(int bi=0;bi<4;bi++) if((b>>bi)&1) sw += popc4(a>>(bi+1));
    int k = idx_of(a^b);
    int c = t.cnt[k];
    t.ii[k][c]=(signed char)i; t.jj[k][c]=(signed char)j;
    t.ss[k][c]=(sw&1)? -1.0f : 1.0f;
    t.cnt[k]=c+1;
  }
  return t;
}
} // namespace ga

__device__ const ga::GPTab GPT = ga::make_gptab();
__constant__ int GRADE16[16] = {0,1,1,1,1,2,2,2,2,2,2,3,3,3,3,4};
// blades with INNER==1: idx {0,2,3,4,7,9,10,14} -> mask 0x469D; compressed pos:
__constant__ int CPOS16[16] = {0,-1,1,2,3,-1,-1,4,-1,5,6,-1,-1,-1,7,-1};

#define NTOK 16384   // B*N
#define NSEQ 4096
#define NB 4
#define QP 64        // q/k row stride (40 real feats + pads; 128B rows)
#define VTROWS 80    // v tile rows (feats)
#define NW 8         // waves per attention block (key-split factor)
#define THR2 11.54f  // defer-max threshold in log2 domain (= 8 nats)

// --------------------------------------------------------------------------
// K1: h[token][o][c] = equi_linear(mv, w_in); mv sparse.
// --------------------------------------------------------------------------
__global__ __launch_bounds__(256) void k_init_h(
    const float* __restrict__ x, const float* __restrict__ w_in,
    float* __restrict__ h)
{
  int gid = blockIdx.x*256 + threadIdx.x;      // token*5 + o
  if (gid >= NTOK*5) return;
  int o = gid % 5, token = gid / 5;
  const float* xt = x + (size_t)token*35;
  const float* w0 = w_in + o*32;               // grade-0 block, row o
  float s = w0[0];                             // mv[0][0] = 1.0
  #pragma unroll
  for (int i=1;i<32;i++) s += w0[i]*xt[i];
  float w2c = w_in[2*160 + o*32 + 0];          // grade-2, input channel 0
  float* ht = h + (size_t)token*80 + o*16;
  #pragma unroll
  for (int c=0;c<16;c++) ht[c] = 0.f;
  ht[0] = s;
  ht[5] = w2c*xt[32];
  ht[6] = w2c*xt[33];
  ht[8] = w2c*xt[34];
}

// --------------------------------------------------------------------------
// K2: fused equi_layernorm + q,k,v equi_linear -> fp16 staging.
// q/k: [token][64] (feats 0..39 real, 40..47 zero, 48..63 never read);
// q pre-scaled by scale*log2(e).
// v: TILE-MAJOR vt[b][tile=n/32][feat(80)][n&31].
// --------------------------------------------------------------------------
__global__ __launch_bounds__(256) void k_ln_qkv(
    const float* __restrict__ h,
    const float* __restrict__ wq, const float* __restrict__ wk,
    const float* __restrict__ wv,
    _Float16* __restrict__ qf, _Float16* __restrict__ kf,
    _Float16* __restrict__ vf)
{
  int tid = threadIdx.x;
  int c   = tid & 15;
  int token = blockIdx.x*16 + (tid>>4);
  int b = token >> 12;          // /4096
  int n = token & 4095;
  int vt_tile = b*128 + (n>>5);
  int vt_col  = n & 31;
  const float* ht = h + (size_t)token*80;
  float hv[5];
  #pragma unroll
  for (int i=0;i<5;i++) hv[i] = ht[i*16 + c];
  bool inner = (0x469D >> c) & 1;
  float part = 0.f;
  if (inner) {
    #pragma unroll
    for (int i=0;i<5;i++) part += hv[i]*hv[i];
  }
  part += __shfl_xor(part, 1);
  part += __shfl_xor(part, 2);
  part += __shfl_xor(part, 4);
  part += __shfl_xor(part, 8);
  float denom = sqrtf(part*(1.f/80.f) + 1e-6f);
  float rinv = 1.f/denom;
  float rln[5];
  #pragma unroll
  for (int i=0;i<5;i++) rln[i] = hv[i]*rinv;

  int g = GRADE16[c];
  int cp = CPOS16[c];
  // (1/sqrt(16*5)) * log2(e): logits land in log2 domain -> exp2 softmax
  const float scaleq = 0.16129820906f;
  #pragma unroll
  for (int o=0;o<5;o++) {
    const float* wqr = wq + g*25 + o*5;
    const float* wkr = wk + g*25 + o*5;
    const float* wvr = wv + g*25 + o*5;
    float aq=0.f, ak=0.f, av=0.f;
    #pragma unroll
    for (int i=0;i<5;i++) {
      aq += rln[i]*wqr[i];
      ak += rln[i]*wkr[i];
      av += rln[i]*wvr[i];
    }
    vf[((size_t)vt_tile*VTROWS + o*16 + c)*32 + vt_col] = (_Float16)av;
    if (inner) {
      size_t qo = (size_t)token*QP + o*8 + cp;
      qf[qo] = (_Float16)(aq*scaleq);
      kf[qo] = (_Float16)ak;
    }
  }
  // zero pads: feats 40..47 (48..63 are never read by the MFMA frags)
  if (c < 8) {
    size_t po = (size_t)token*QP + 40 + c;
    qf[po] = (_Float16)0.f;
    kf[po] = (_Float16)0.f;
  }
}

// --------------------------------------------------------------------------
// K3: fp16 MFMA flash attention, 8-way intra-block key-split with LDS merge,
// fused epilogue (normalize + wo projection + residual). Block = 512 thr =
// 8 waves, one 32-row Q-tile; wave w covers keys [w*512, (w+1)*512).
// 1D grid, XCD<->batch swizzle: bid%8 -> XCD (empirical round-robin);
// batch = xcd&3 so each XCD streams ONE batch's K/V (L2-resident).
// Swapped QK^T: S = mfma(A=K, B=Q) -> C col (lane&31) = q-row.
// K and V both register-prefetched one 32-key tile ahead.
// --------------------------------------------------------------------------
__global__ __launch_bounds__(512, 4) void k_attn_mfma(
    const _Float16* __restrict__ qf, const _Float16* __restrict__ kf,
    const _Float16* __restrict__ vf,
    const float* __restrict__ wo, float* __restrict__ h)
{
  __shared__ __align__(16) float satt[32][80];
  __shared__ __align__(16) float ldsb[NW][32];
  __shared__ __align__(16) float sM[NW][32];
  __shared__ __align__(16) float sL[NW][32];
  __shared__ __align__(16) float sMax[32];
  __shared__ __align__(16) float sInv[32];
  __shared__ float sWo[125];
  int tid = threadIdx.x;
  int w  = tid >> 6;
  int ln = tid & 31;
  int hf = (tid >> 5) & 1;
  // XCD-aware decode: bid%8 = XCD (round-robin). batch pinned per XCD pair.
  int bid = blockIdx.x;
  int xcd = bid & 7;
  int jj  = bid >> 3;                 // 0..63
  int b   = xcd & 3;
  int qt  = (xcd >> 2)*64 + jj;       // 0..127
  int rowbase = b*NSEQ + qt*32;

  for (int i=tid; i<125; i+=512) sWo[i] = wo[i];
  for (int i=tid; i<2560; i+=512) ((float*)satt)[i] = 0.f;

  // Q frags (B operand): B[k][j]: j=lane&31=qrow, k=(lane>>5)*8+e
  const _Float16* qp = qf + (size_t)(rowbase + ln)*QP + hf*8;
  f16x8 q0 = *(const f16x8*)(qp);
  f16x8 q1 = *(const f16x8*)(qp + 16);
  f16x8 q2 = *(const f16x8*)(qp + 32);

  f32x16 acc0, acc1, acc2;
  #pragma unroll
  for (int r=0;r<16;r++){ acc0[r]=0.f; acc1[r]=0.f; acc2[r]=0.f; }
  float m = -1e30f, lsum = 0.f;

  // per-lane offsets into a V tile (tile-major: [feat(80)][32 keys])
  int voff0 = (     ln)*32 + hf*8;
  int voff1 = (32 + ln)*32 + hf*8;
  int voff2 = (64 + (ln&15))*32 + hf*8;   // feats 64..79; cols>=16 duplicated

  int kbeg = w*(NSEQ/NW), kend = kbeg + NSEQ/NW;
  const _Float16* kbase = kf + (size_t)(b*NSEQ + ln)*QP + hf*8;
  const _Float16* vbase = vf + (size_t)(b*128)*(VTROWS*32);

  // prologue: preload first K and V tiles
  const _Float16* kp0 = kbase + (size_t)kbeg*QP;
  f16x8 kc0 = *(const f16x8*)(kp0);
  f16x8 kc1 = *(const f16x8*)(kp0 + 16);
  f16x8 kc2 = *(const f16x8*)(kp0 + 32);
  const _Float16* vp0 = vbase + (size_t)(kbeg>>5)*(VTROWS*32);
  f16x8 vc00 = *(const f16x8*)(vp0 + voff0);
  f16x8 vc01 = *(const f16x8*)(vp0 + voff0 + 16);
  f16x8 vc10 = *(const f16x8*)(vp0 + voff1);
  f16x8 vc11 = *(const f16x8*)(vp0 + voff1 + 16);
  f16x8 vc20 = *(const f16x8*)(vp0 + voff2);
  f16x8 vc21 = *(const f16x8*)(vp0 + voff2 + 16);

  for (int koff=kbeg; koff<kend; koff+=32) {
    // QK^T on prefetched K frags: A[i][k]: i=key, k=feat
    f32x16 S;
    #pragma unroll
    for (int r=0;r<16;r++) S[r]=0.f;
    S = __builtin_amdgcn_mfma_f32_32x32x16_f16(kc0, q0, S, 0,0,0);
    S = __builtin_amdgcn_mfma_f32_32x32x16_f16(kc1, q1, S, 0,0,0);
    S = __builtin_amdgcn_mfma_f32_32x32x16_f16(kc2, q2, S, 0,0,0);
    // S frag: lane holds q-row (ln); 16 keys: key(r) = (r&3)+8*(r>>2)+4*hf

    // prefetch next K and V tiles (wraps on last iter; harmless dup)
    int knext = koff + 32; if (knext >= kend) knext = kbeg;
    const _Float16* kp = kbase + (size_t)knext*QP;
    f16x8 kn0 = *(const f16x8*)(kp);
    f16x8 kn1 = *(const f16x8*)(kp + 16);
    f16x8 kn2 = *(const f16x8*)(kp + 32);
    const _Float16* vp = vbase + (size_t)(knext>>5)*(VTROWS*32);
    f16x8 vn00 = *(const f16x8*)(vp + voff0);
    f16x8 vn01 = *(const f16x8*)(vp + voff0 + 16);
    f16x8 vn10 = *(const f16x8*)(vp + voff1);
    f16x8 vn11 = *(const f16x8*)(vp + voff1 + 16);
    f16x8 vn20 = *(const f16x8*)(vp + voff2);
    f16x8 vn21 = *(const f16x8*)(vp + voff2 + 16);

    // tile max: balanced tree (log2-domain logits)
    float t01 = fmaxf(S[0],S[1]),   t23 = fmaxf(S[2],S[3]);
    float t45 = fmaxf(S[4],S[5]),   t67 = fmaxf(S[6],S[7]);
    float t89 = fmaxf(S[8],S[9]),   tab = fmaxf(S[10],S[11]);
    float tcd = fmaxf(S[12],S[13]), tef = fmaxf(S[14],S[15]);
    float u0 = fmaxf(t01,t23), u1 = fmaxf(t45,t67);
    float u2 = fmaxf(t89,tab), u3 = fmaxf(tcd,tef);
    float tmax = fmaxf(fmaxf(u0,u1), fmaxf(u2,u3));
    tmax = fmaxf(tmax, __shfl_xor(tmax, 32));
    if (!__all(tmax <= m + THR2)) {
      float mn = fmaxf(m, tmax);
      float f = exp2f(m - mn);
      if (hf==0) ldsb[w][ln] = f;
      float fv[16];
      *(float4*)&fv[0]  = *(const float4*)&ldsb[w][ 0 + hf*4];
      *(float4*)&fv[4]  = *(const float4*)&ldsb[w][ 8 + hf*4];
      *(float4*)&fv[8]  = *(const float4*)&ldsb[w][16 + hf*4];
      *(float4*)&fv[12] = *(const float4*)&ldsb[w][24 + hf*4];
      #pragma unroll
      for (int r=0;r<16;r++){ float fr=fv[r]; acc0[r]*=fr; acc1[r]*=fr; acc2[r]*=fr; }
      lsum *= f;
      m = mn;
    }
    float p[16];
    #pragma unroll
    for (int r=0;r<16;r++) p[r] = exp2f(S[r] - m);
    // tree-sum of p
    float s0 = (p[0]+p[1]) + (p[2]+p[3]);
    float s1 = (p[4]+p[5]) + (p[6]+p[7]);
    float s2 = (p[8]+p[9]) + (p[10]+p[11]);
    float s3 = (p[12]+p[13]) + (p[14]+p[15]);
    float ls = (s0+s1) + (s2+s3);
    ls += __shfl_xor(ls, 32);
    lsum += ls;

    // pack P -> fp16 pairs; key-order pairs (p[2e],p[2e+1])
    unsigned pk[8];
    #pragma unroll
    for (int e=0;e<8;e++) {
      union { fp16v2 h2; unsigned u; } cv;
      cv.h2 = __builtin_amdgcn_cvt_pkrtz(p[2*e], p[2*e+1]);
      pk[e] = cv.u;
    }
    // exchange halves: A0 covers keys 0..15, A1 keys 16..31
    union { unsigned u[4]; f16x8 v; } A0, A1;
    {
      unsigned sa = hf ? pk[0] : pk[2], sb = hf ? pk[1] : pk[3];
      unsigned ra = __shfl_xor((int)sa,32), rb = __shfl_xor((int)sb,32);
      unsigned sc = hf ? pk[4] : pk[6], sd = hf ? pk[5] : pk[7];
      unsigned rc = __shfl_xor((int)sc,32), rd = __shfl_xor((int)sd,32);
      A0.u[0] = hf ? ra    : pk[0];  A0.u[1] = hf ? rb    : pk[1];
      A0.u[2] = hf ? pk[2] : ra;     A0.u[3] = hf ? pk[3] : rb;
      A1.u[0] = hf ? rc    : pk[4];  A1.u[1] = hf ? rd    : pk[5];
      A1.u[2] = hf ? pk[6] : rc;     A1.u[3] = hf ? pk[7] : rd;
    }

    // PV: B[k][j]: j=lane&31=feat(in 32-block), k=(lane>>5)*8+e=key
    acc0 = __builtin_amdgcn_mfma_f32_32x32x16_f16(A0.v, vc00, acc0, 0,0,0);
    acc0 = __builtin_amdgcn_mfma_f32_32x32x16_f16(A1.v, vc01, acc0, 0,0,0);
    acc1 = __builtin_amdgcn_mfma_f32_32x32x16_f16(A0.v, vc10, acc1, 0,0,0);
    acc1 = __builtin_amdgcn_mfma_f32_32x32x16_f16(A1.v, vc11, acc1, 0,0,0);
    acc2 = __builtin_amdgcn_mfma_f32_32x32x16_f16(A0.v, vc20, acc2, 0,0,0);
    acc2 = __builtin_amdgcn_mfma_f32_32x32x16_f16(A1.v, vc21, acc2, 0,0,0);

    kc0 = kn0; kc1 = kn1; kc2 = kn2;
    vc00 = vn00; vc01 = vn01; vc10 = vn10;
    vc11 = vn11; vc20 = vn20; vc21 = vn21;
  }

  // ---- cross-wave merge ----
  if (hf==0) { sM[w][ln] = m; sL[w][ln] = lsum; }
  __syncthreads();
  if (tid < 32) {
    float M = sM[0][tid];
    #pragma unroll
    for (int u=1;u<NW;u++) M = fmaxf(M, sM[u][tid]);
    float L = 0.f;
    #pragma unroll
    for (int u=0;u<NW;u++) L += exp2f(sM[u][tid] - M)*sL[u][tid];
    sMax[tid] = M;
    sInv[tid] = 1.f/L;
  }
  __syncthreads();
  // per-wave scale factor in C-frag row layout, accumulate into satt
  {
    float sm[16], sx[16];
    *(float4*)&sm[0]  = *(const float4*)&sM[w][ 0 + hf*4];
    *(float4*)&sm[4]  = *(const float4*)&sM[w][ 8 + hf*4];
    *(float4*)&sm[8]  = *(const float4*)&sM[w][16 + hf*4];
    *(float4*)&sm[12] = *(const float4*)&sM[w][24 + hf*4];
    *(float4*)&sx[0]  = *(const float4*)&sMax[ 0 + hf*4];
    *(float4*)&sx[4]  = *(const float4*)&sMax[ 8 + hf*4];
    *(float4*)&sx[8]  = *(const float4*)&sMax[16 + hf*4];
    *(float4*)&sx[12] = *(const float4*)&sMax[24 + hf*4];
    #pragma unroll
    for (int r=0;r<16;r++) {
      int row = (r&3) + 8*(r>>2) + 4*hf;
      float f = exp2f(sm[r] - sx[r]);
      atomicAdd(&satt[row][ln],    f*acc0[r]);
      atomicAdd(&satt[row][32+ln], f*acc1[r]);
      if (ln < 16) atomicAdd(&satt[row][64+ln], f*acc2[r]);
    }
  }
  __syncthreads();
  // wo-projection + residual: h[rowbase*80 + flat] += proj
  float* hb = h + (size_t)rowbase*80;
  #pragma unroll
  for (int e=0;e<5;e++) {
    int flat = e*512 + tid;
    int rr = flat/80, oc = flat - rr*80;
    int o = oc>>4, c = oc&15;
    int g = GRADE16[c];
    const float* wor = sWo + g*25 + o*5;
    float a = 0.f;
    #pragma unroll
    for (int i=0;i<5;i++) a += satt[rr][i*16+c]*wor[i];
    hb[flat] += a*sInv[rr];
  }
}

// --------------------------------------------------------------------------
// K4: fused equi_layernorm + MLP (w1 -> geometric product -> gated gelu ->
// w2) + residual. 16 threads/token (one per output blade), 16 tokens/block.
// --------------------------------------------------------------------------
__global__ __launch_bounds__(256) void k_mlp(
    float* __restrict__ h,
    const float* __restrict__ w1, const float* __restrict__ w2)
{
  __shared__ float sh1[16][10][16];
  int tid = threadIdx.x;
  int c   = tid & 15;
  int tl  = tid >> 4;
  int token = blockIdx.x*16 + tl;
  float* ht = h + (size_t)token*80;
  float hv[5];
  #pragma unroll
  for (int i=0;i<5;i++) hv[i] = ht[i*16 + c];
  bool inner = (0x469D >> c) & 1;
  float part = 0.f;
  if (inner) {
    #pragma unroll
    for (int i=0;i<5;i++) part += hv[i]*hv[i];
  }
  part += __shfl_xor(part, 1);
  part += __shfl_xor(part, 2);
  part += __shfl_xor(part, 4);
  part += __shfl_xor(part, 8);
  float denom = sqrtf(part*(1.f/80.f) + 1e-6f);
  float rinv = 1.f/denom;
  float rln[5];
  #pragma unroll
  for (int i=0;i<5;i++) rln[i] = hv[i]*rinv;

  int g = GRADE16[c];
  #pragma unroll
  for (int o=0;o<10;o++) {
    const float* w1r = w1 + g*50 + o*5;
    float a=0.f;
    #pragma unroll
    for (int i=0;i<5;i++) a += rln[i]*w1r[i];
    sh1[tl][o][c] = a;
  }
  __syncthreads();
  // geometric product: thread c computes gp[hh][c] for all 5 channels
  float gpv[5];
  #pragma unroll
  for (int hh=0; hh<5; hh++) {
    float a = 0.f;
    int n = GPT.cnt[c];
    for (int e=0; e<n; ++e) {
      a += GPT.ss[c][e]*sh1[tl][hh][GPT.ii[c][e]]*sh1[tl][5+hh][GPT.jj[c][e]];
    }
    gpv[hh] = a;
  }
  // gate by gelu(scalar component) -- lane c=0 of this token's 16-lane group
  int base = (tid & 63) & ~15;
  #pragma unroll
  for (int hh=0;hh<5;hh++) {
    float g0 = __shfl(gpv[hh], base);
    float u  = 0.7978845608028654f*(g0 + 0.044715f*g0*g0*g0);
    float gate = 0.5f*g0*(1.f + tanhf(u));
    gpv[hh] *= gate;
  }
  // final equi_linear (w2) + residual
  #pragma unroll
  for (int o=0;o<5;o++) {
    const float* w2r = w2 + g*25 + o*5;
    float a=0.f;
    #pragma unroll
    for (int i=0;i<5;i++) a += gpv[i]*w2r[i];
    ht[o*16+c] += a;
  }
}

// --------------------------------------------------------------------------
// K5: final equi_linear (w_out) + output extraction.
// --------------------------------------------------------------------------
__global__ __launch_bounds__(256) void k_out(
    const float* __restrict__ h, const float* __restrict__ w_out,
    float* __restrict__ out)
{
  int gid = blockIdx.x*256 + threadIdx.x;
  if (gid >= NTOK*35) return;
  int j = gid % 35, token = gid / 35;
  const float* ht = h + (size_t)token*80;
  float a = 0.f;
  if (j < 32) {
    const float* w = w_out + j*5;              // grade 0, row j
    #pragma unroll
    for (int i=0;i<5;i++) a += ht[i*16 + 0]*w[i];
  } else {
    int c = (j==32)?5:((j==33)?6:8);
    const float* w = w_out + 2*160 + 0*5;      // grade 2, row 0
    #pragma unroll
    for (int i=0;i<5;i++) a += ht[i*16 + c]*w[i];
  }
  out[gid] = a;
}

// --------------------------------------------------------------------------
extern "C" void kernel_launch(void* const* d_in, const int* in_sizes, int n_in,
                              void* d_out, int out_size, void* d_ws, size_t ws_size,
                              hipStream_t stream) {
  const float* x     = (const float*)d_in[0];
  const float* w_in  = (const float*)d_in[1];
  const float* w_out = (const float*)d_in[2];
  const float* wq    = (const float*)d_in[3];
  const float* wk    = (const float*)d_in[4];
  const float* wv    = (const float*)d_in[5];
  const float* wo    = (const float*)d_in[6];
  const float* w1    = (const float*)d_in[7];
  const float* w2    = (const float*)d_in[8];
  float* out = (float*)d_out;

  // workspace carve: h fp32 (5.24MB) + qf,kf fp16 [64/row] (2.1MB each) +
  // vf fp16 tiled (2.62MB)  => ~12.1MB total.
  char* p = (char*)d_ws;
  float* h = (float*)p;              p += (size_t)NTOK*80*4;
  _Float16* qf = (_Float16*)p;       p += (size_t)NTOK*QP*2;
  _Float16* kf = (_Float16*)p;       p += (size_t)NTOK*QP*2;
  _Float16* vf = (_Float16*)p;

  k_init_h<<<(NTOK*5 + 255)/256, 256, 0, stream>>>(x, w_in, h);
  for (int blk=0; blk<3; ++blk) {
    k_ln_qkv<<<NTOK/16, 256, 0, stream>>>(h, wq+blk*125, wk+blk*125, wv+blk*125,
                                          qf, kf, vf);
    k_attn_mfma<<<512, 512, 0, stream>>>(qf, kf, vf, wo+blk*125, h);
    k_mlp<<<NTOK/16, 256, 0, stream>>>(h, w1+blk*250, w2+blk*125);
  }
  k_out<<<(NTOK*35 + 255)/256, 256, 0, stream>>>(h, w_out, out);
}

// Round 9
// 316.801 us; speedup vs baseline: 2.2498x; 2.2498x over previous
//
#include <hip/hip_runtime.h>
#include <hip/hip_bf16.h>
#include <math.h>

typedef __attribute__((ext_vector_type(8)))  _Float16 f16x8;
typedef __attribute__((ext_vector_type(2)))  __fp16   fp16v2;
typedef __attribute__((ext_vector_type(16))) float    f32x16;

// ---------------------------------------------------------------------------
// GATr forward on MI355X. B=4, N=4096, H=5, BLK=3, INV=32, 16 blades.
// Metric (0,1,1,1) PGA. Blade order sorted by (grade, mask).
// Attention: fp16 MFMA, exp2 softmax, K+V register prefetch (depth 1) with
// REAL register headroom (launch_bounds(256,2) -> no spill), 4-way key-split.
// ---------------------------------------------------------------------------

namespace ga {
constexpr int MASKS[16] = {0,1,2,4,8,3,5,6,9,10,12,7,11,13,14,15};
constexpr int popc4(int x){ return (x&1)+((x>>1)&1)+((x>>2)&1)+((x>>3)&1); }
constexpr int idx_of(int m){ int r=-1; for(int i=0;i<16;i++) if(MASKS[i]==m) r=i; return r; }
struct GPTab {
  int cnt[16];
  signed char ii[16][16];
  signed char jj[16][16];
  float ss[16][16];
};
constexpr GPTab make_gptab(){
  GPTab t{};
  for(int i=0;i<16;i++) for(int j=0;j<16;j++){
    int a=MASKS[i], b=MASKS[j];
    if((a&b&1)!=0) continue;           // e0^2 = 0 kills the term
    int sw=0;
    for(int bi=0;bi<4;bi++) if((b>>bi)&1) sw += popc4(a>>(bi+1));
    int k = idx_of(a^b);
    int c = t.cnt[k];
    t.ii[k][c]=(signed char)i; t.jj[k][c]=(signed char)j;
    t.ss[k][c]=(sw&1)? -1.0f : 1.0f;
    t.cnt[k]=c+1;
  }
  return t;
}
} // namespace ga

__device__ const ga::GPTab GPT = ga::make_gptab();
__constant__ int GRADE16[16] = {0,1,1,1,1,2,2,2,2,2,2,3,3,3,3,4};
// blades with INNER==1: idx {0,2,3,4,7,9,10,14} -> mask 0x469D; compressed pos:
__constant__ int CPOS16[16] = {0,-1,1,2,3,-1,-1,4,-1,5,6,-1,-1,-1,7,-1};

#define NTOK 16384   // B*N
#define NSEQ 4096
#define NB 4
#define QP 64        // q/k row stride (40 real feats + pads; 128B rows)
#define VTROWS 80    // v tile rows (feats)
#define NW 4         // waves per attention block (key-split factor)
#define THR2 11.54f  // defer-max threshold in log2 domain (= 8 nats)

// --------------------------------------------------------------------------
// K1: h[token][o][c] = equi_linear(mv, w_in); mv sparse.
// --------------------------------------------------------------------------
__global__ __launch_bounds__(256) void k_init_h(
    const float* __restrict__ x, const float* __restrict__ w_in,
    float* __restrict__ h)
{
  int gid = blockIdx.x*256 + threadIdx.x;      // token*5 + o
  if (gid >= NTOK*5) return;
  int o = gid % 5, token = gid / 5;
  const float* xt = x + (size_t)token*35;
  const float* w0 = w_in + o*32;               // grade-0 block, row o
  float s = w0[0];                             // mv[0][0] = 1.0
  #pragma unroll
  for (int i=1;i<32;i++) s += w0[i]*xt[i];
  float w2c = w_in[2*160 + o*32 + 0];          // grade-2, input channel 0
  float* ht = h + (size_t)token*80 + o*16;
  #pragma unroll
  for (int c=0;c<16;c++) ht[c] = 0.f;
  ht[0] = s;
  ht[5] = w2c*xt[32];
  ht[6] = w2c*xt[33];
  ht[8] = w2c*xt[34];
}

// --------------------------------------------------------------------------
// K2: fused equi_layernorm + q,k,v equi_linear -> fp16 staging.
// q/k: [token][64] (feats 0..39 real, 40..47 zero, 48..63 never read);
// q pre-scaled by scale*log2(e).
// v: TILE-MAJOR vt[b][tile=n/32][feat(80)][n&31].
// --------------------------------------------------------------------------
__global__ __launch_bounds__(256) void k_ln_qkv(
    const float* __restrict__ h,
    const float* __restrict__ wq, const float* __restrict__ wk,
    const float* __restrict__ wv,
    _Float16* __restrict__ qf, _Float16* __restrict__ kf,
    _Float16* __restrict__ vf)
{
  int tid = threadIdx.x;
  int c   = tid & 15;
  int token = blockIdx.x*16 + (tid>>4);
  int b = token >> 12;          // /4096
  int n = token & 4095;
  int vt_tile = b*128 + (n>>5);
  int vt_col  = n & 31;
  const float* ht = h + (size_t)token*80;
  float hv[5];
  #pragma unroll
  for (int i=0;i<5;i++) hv[i] = ht[i*16 + c];
  bool inner = (0x469D >> c) & 1;
  float part = 0.f;
  if (inner) {
    #pragma unroll
    for (int i=0;i<5;i++) part += hv[i]*hv[i];
  }
  part += __shfl_xor(part, 1);
  part += __shfl_xor(part, 2);
  part += __shfl_xor(part, 4);
  part += __shfl_xor(part, 8);
  float denom = sqrtf(part*(1.f/80.f) + 1e-6f);
  float rinv = 1.f/denom;
  float rln[5];
  #pragma unroll
  for (int i=0;i<5;i++) rln[i] = hv[i]*rinv;

  int g = GRADE16[c];
  int cp = CPOS16[c];
  // (1/sqrt(16*5)) * log2(e): logits land in log2 domain -> exp2 softmax
  const float scaleq = 0.16129820906f;
  #pragma unroll
  for (int o=0;o<5;o++) {
    const float* wqr = wq + g*25 + o*5;
    const float* wkr = wk + g*25 + o*5;
    const float* wvr = wv + g*25 + o*5;
    float aq=0.f, ak=0.f, av=0.f;
    #pragma unroll
    for (int i=0;i<5;i++) {
      aq += rln[i]*wqr[i];
      ak += rln[i]*wkr[i];
      av += rln[i]*wvr[i];
    }
    vf[((size_t)vt_tile*VTROWS + o*16 + c)*32 + vt_col] = (_Float16)av;
    if (inner) {
      size_t qo = (size_t)token*QP + o*8 + cp;
      qf[qo] = (_Float16)(aq*scaleq);
      kf[qo] = (_Float16)ak;
    }
  }
  // zero pads: feats 40..47 (48..63 are never read by the MFMA frags)
  if (c < 8) {
    size_t po = (size_t)token*QP + 40 + c;
    qf[po] = (_Float16)0.f;
    kf[po] = (_Float16)0.f;
  }
}

// --------------------------------------------------------------------------
// K3: fp16 MFMA flash attention, 4-way intra-block key-split with LDS merge,
// fused epilogue (normalize + wo projection + residual). Block = 256 thr =
// 4 waves, one 32-row Q-tile; wave w covers keys [w*1024, (w+1)*1024).
// Swapped QK^T: S = mfma(A=K, B=Q) -> C col (lane&31) = q-row.
// K and V both register-prefetched one 32-key tile ahead.
// launch_bounds(256,2): VGPR cap 256 so the prefetch does NOT spill.
// --------------------------------------------------------------------------
__global__ __launch_bounds__(256, 2) void k_attn_mfma(
    const _Float16* __restrict__ qf, const _Float16* __restrict__ kf,
    const _Float16* __restrict__ vf,
    const float* __restrict__ wo, float* __restrict__ h)
{
  __shared__ __align__(16) float satt[32][80];
  __shared__ __align__(16) float ldsb[NW][32];
  __shared__ __align__(16) float sM[NW][32];
  __shared__ __align__(16) float sL[NW][32];
  __shared__ __align__(16) float sMax[32];
  __shared__ __align__(16) float sInv[32];
  __shared__ float sWo[125];
  int tid = threadIdx.x;
  int w  = tid >> 6;
  int ln = tid & 31;
  int hf = (tid >> 5) & 1;
  int b  = blockIdx.y;
  int rowbase = b*NSEQ + blockIdx.x*32;

  for (int i=tid; i<125; i+=256) sWo[i] = wo[i];
  for (int i=tid; i<2560; i+=256) ((float*)satt)[i] = 0.f;

  // Q frags (B operand): B[k][j]: j=lane&31=qrow, k=(lane>>5)*8+e
  const _Float16* qp = qf + (size_t)(rowbase + ln)*QP + hf*8;
  f16x8 q0 = *(const f16x8*)(qp);
  f16x8 q1 = *(const f16x8*)(qp + 16);
  f16x8 q2 = *(const f16x8*)(qp + 32);

  f32x16 acc0, acc1, acc2;
  #pragma unroll
  for (int r=0;r<16;r++){ acc0[r]=0.f; acc1[r]=0.f; acc2[r]=0.f; }
  float m = -1e30f, lsum = 0.f;

  // per-lane offsets into a V tile (tile-major: [feat(80)][32 keys])
  int voff0 = (     ln)*32 + hf*8;
  int voff1 = (32 + ln)*32 + hf*8;
  int voff2 = (64 + (ln&15))*32 + hf*8;   // feats 64..79; cols>=16 duplicated

  int kbeg = w*(NSEQ/NW), kend = kbeg + NSEQ/NW;
  const _Float16* kbase = kf + (size_t)(b*NSEQ + ln)*QP + hf*8;
  const _Float16* vbase = vf + (size_t)(b*128)*(VTROWS*32);

  // prologue: preload first K and V tiles
  const _Float16* kp0 = kbase + (size_t)kbeg*QP;
  f16x8 kc0 = *(const f16x8*)(kp0);
  f16x8 kc1 = *(const f16x8*)(kp0 + 16);
  f16x8 kc2 = *(const f16x8*)(kp0 + 32);
  const _Float16* vp0 = vbase + (size_t)(kbeg>>5)*(VTROWS*32);
  f16x8 vc00 = *(const f16x8*)(vp0 + voff0);
  f16x8 vc01 = *(const f16x8*)(vp0 + voff0 + 16);
  f16x8 vc10 = *(const f16x8*)(vp0 + voff1);
  f16x8 vc11 = *(const f16x8*)(vp0 + voff1 + 16);
  f16x8 vc20 = *(const f16x8*)(vp0 + voff2);
  f16x8 vc21 = *(const f16x8*)(vp0 + voff2 + 16);

  for (int koff=kbeg; koff<kend; koff+=32) {
    // QK^T on prefetched K frags: A[i][k]: i=key, k=feat
    f32x16 S;
    #pragma unroll
    for (int r=0;r<16;r++) S[r]=0.f;
    S = __builtin_amdgcn_mfma_f32_32x32x16_f16(kc0, q0, S, 0,0,0);
    S = __builtin_amdgcn_mfma_f32_32x32x16_f16(kc1, q1, S, 0,0,0);
    S = __builtin_amdgcn_mfma_f32_32x32x16_f16(kc2, q2, S, 0,0,0);
    // S frag: lane holds q-row (ln); 16 keys: key(r) = (r&3)+8*(r>>2)+4*hf

    // prefetch next K and V tiles (wraps on last iter; harmless dup)
    int knext = koff + 32; if (knext >= kend) knext = kbeg;
    const _Float16* kp = kbase + (size_t)knext*QP;
    f16x8 kn0 = *(const f16x8*)(kp);
    f16x8 kn1 = *(const f16x8*)(kp + 16);
    f16x8 kn2 = *(const f16x8*)(kp + 32);
    const _Float16* vp = vbase + (size_t)(knext>>5)*(VTROWS*32);
    f16x8 vn00 = *(const f16x8*)(vp + voff0);
    f16x8 vn01 = *(const f16x8*)(vp + voff0 + 16);
    f16x8 vn10 = *(const f16x8*)(vp + voff1);
    f16x8 vn11 = *(const f16x8*)(vp + voff1 + 16);
    f16x8 vn20 = *(const f16x8*)(vp + voff2);
    f16x8 vn21 = *(const f16x8*)(vp + voff2 + 16);

    // tile max: balanced tree (log2-domain logits)
    float t01 = fmaxf(S[0],S[1]),   t23 = fmaxf(S[2],S[3]);
    float t45 = fmaxf(S[4],S[5]),   t67 = fmaxf(S[6],S[7]);
    float t89 = fmaxf(S[8],S[9]),   tab = fmaxf(S[10],S[11]);
    float tcd = fmaxf(S[12],S[13]), tef = fmaxf(S[14],S[15]);
    float u0 = fmaxf(t01,t23), u1 = fmaxf(t45,t67);
    float u2 = fmaxf(t89,tab), u3 = fmaxf(tcd,tef);
    float tmax = fmaxf(fmaxf(u0,u1), fmaxf(u2,u3));
    tmax = fmaxf(tmax, __shfl_xor(tmax, 32));
    if (!__all(tmax <= m + THR2)) {
      float mn = fmaxf(m, tmax);
      float f = exp2f(m - mn);
      if (hf==0) ldsb[w][ln] = f;
      float fv[16];
      *(float4*)&fv[0]  = *(const float4*)&ldsb[w][ 0 + hf*4];
      *(float4*)&fv[4]  = *(const float4*)&ldsb[w][ 8 + hf*4];
      *(float4*)&fv[8]  = *(const float4*)&ldsb[w][16 + hf*4];
      *(float4*)&fv[12] = *(const float4*)&ldsb[w][24 + hf*4];
      #pragma unroll
      for (int r=0;r<16;r++){ float fr=fv[r]; acc0[r]*=fr; acc1[r]*=fr; acc2[r]*=fr; }
      lsum *= f;
      m = mn;
    }
    float p[16];
    #pragma unroll
    for (int r=0;r<16;r++) p[r] = exp2f(S[r] - m);
    // tree-sum of p
    float s0 = (p[0]+p[1]) + (p[2]+p[3]);
    float s1 = (p[4]+p[5]) + (p[6]+p[7]);
    float s2 = (p[8]+p[9]) + (p[10]+p[11]);
    float s3 = (p[12]+p[13]) + (p[14]+p[15]);
    float ls = (s0+s1) + (s2+s3);
    ls += __shfl_xor(ls, 32);
    lsum += ls;

    // pack P -> fp16 pairs; key-order pairs (p[2e],p[2e+1])
    unsigned pk[8];
    #pragma unroll
    for (int e=0;e<8;e++) {
      union { fp16v2 h2; unsigned u; } cv;
      cv.h2 = __builtin_amdgcn_cvt_pkrtz(p[2*e], p[2*e+1]);
      pk[e] = cv.u;
    }
    // exchange halves: A0 covers keys 0..15, A1 keys 16..31
    union { unsigned u[4]; f16x8 v; } A0, A1;
    {
      unsigned sa = hf ? pk[0] : pk[2], sb = hf ? pk[1] : pk[3];
      unsigned ra = __shfl_xor((int)sa,32), rb = __shfl_xor((int)sb,32);
      unsigned sc = hf ? pk[4] : pk[6], sd = hf ? pk[5] : pk[7];
      unsigned rc = __shfl_xor((int)sc,32), rd = __shfl_xor((int)sd,32);
      A0.u[0] = hf ? ra    : pk[0];  A0.u[1] = hf ? rb    : pk[1];
      A0.u[2] = hf ? pk[2] : ra;     A0.u[3] = hf ? pk[3] : rb;
      A1.u[0] = hf ? rc    : pk[4];  A1.u[1] = hf ? rd    : pk[5];
      A1.u[2] = hf ? pk[6] : rc;     A1.u[3] = hf ? pk[7] : rd;
    }

    // PV: B[k][j]: j=lane&31=feat(in 32-block), k=(lane>>5)*8+e=key
    acc0 = __builtin_amdgcn_mfma_f32_32x32x16_f16(A0.v, vc00, acc0, 0,0,0);
    acc0 = __builtin_amdgcn_mfma_f32_32x32x16_f16(A1.v, vc01, acc0, 0,0,0);
    acc1 = __builtin_amdgcn_mfma_f32_32x32x16_f16(A0.v, vc10, acc1, 0,0,0);
    acc1 = __builtin_amdgcn_mfma_f32_32x32x16_f16(A1.v, vc11, acc1, 0,0,0);
    acc2 = __builtin_amdgcn_mfma_f32_32x32x16_f16(A0.v, vc20, acc2, 0,0,0);
    acc2 = __builtin_amdgcn_mfma_f32_32x32x16_f16(A1.v, vc21, acc2, 0,0,0);

    kc0 = kn0; kc1 = kn1; kc2 = kn2;
    vc00 = vn00; vc01 = vn01; vc10 = vn10;
    vc11 = vn11; vc20 = vn20; vc21 = vn21;
  }

  // ---- cross-wave merge ----
  if (hf==0) { sM[w][ln] = m; sL[w][ln] = lsum; }
  __syncthreads();
  if (tid < 32) {
    float M = sM[0][tid];
    #pragma unroll
    for (int u=1;u<NW;u++) M = fmaxf(M, sM[u][tid]);
    float L = 0.f;
    #pragma unroll
    for (int u=0;u<NW;u++) L += exp2f(sM[u][tid] - M)*sL[u][tid];
    sMax[tid] = M;
    sInv[tid] = 1.f/L;
  }
  __syncthreads();
  // per-wave scale factor in C-frag row layout, accumulate into satt
  {
    float sm[16], sx[16];
    *(float4*)&sm[0]  = *(const float4*)&sM[w][ 0 + hf*4];
    *(float4*)&sm[4]  = *(const float4*)&sM[w][ 8 + hf*4];
    *(float4*)&sm[8]  = *(const float4*)&sM[w][16 + hf*4];
    *(float4*)&sm[12] = *(const float4*)&sM[w][24 + hf*4];
    *(float4*)&sx[0]  = *(const float4*)&sMax[ 0 + hf*4];
    *(float4*)&sx[4]  = *(const float4*)&sMax[ 8 + hf*4];
    *(float4*)&sx[8]  = *(const float4*)&sMax[16 + hf*4];
    *(float4*)&sx[12] = *(const float4*)&sMax[24 + hf*4];
    #pragma unroll
    for (int r=0;r<16;r++) {
      int row = (r&3) + 8*(r>>2) + 4*hf;
      float f = exp2f(sm[r] - sx[r]);
      atomicAdd(&satt[row][ln],    f*acc0[r]);
      atomicAdd(&satt[row][32+ln], f*acc1[r]);
      if (ln < 16) atomicAdd(&satt[row][64+ln], f*acc2[r]);
    }
  }
  __syncthreads();
  // wo-projection + residual: h[rowbase*80 + flat] += proj
  float* hb = h + (size_t)rowbase*80;
  #pragma unroll
  for (int e=0;e<10;e++) {
    int flat = e*256 + tid;
    int rr = flat/80, oc = flat - rr*80;
    int o = oc>>4, c = oc&15;
    int g = GRADE16[c];
    const float* wor = sWo + g*25 + o*5;
    float a = 0.f;
    #pragma unroll
    for (int i=0;i<5;i++) a += satt[rr][i*16+c]*wor[i];
    hb[flat] += a*sInv[rr];
  }
}

// --------------------------------------------------------------------------
// K4: fused equi_layernorm + MLP (w1 -> geometric product -> gated gelu ->
// w2) + residual. 16 threads/token (one per output blade), 16 tokens/block.
// --------------------------------------------------------------------------
__global__ __launch_bounds__(256) void k_mlp(
    float* __restrict__ h,
    const float* __restrict__ w1, const float* __restrict__ w2)
{
  __shared__ float sh1[16][10][16];
  int tid = threadIdx.x;
  int c   = tid & 15;
  int tl  = tid >> 4;
  int token = blockIdx.x*16 + tl;
  float* ht = h + (size_t)token*80;
  float hv[5];
  #pragma unroll
  for (int i=0;i<5;i++) hv[i] = ht[i*16 + c];
  bool inner = (0x469D >> c) & 1;
  float part = 0.f;
  if (inner) {
    #pragma unroll
    for (int i=0;i<5;i++) part += hv[i]*hv[i];
  }
  part += __shfl_xor(part, 1);
  part += __shfl_xor(part, 2);
  part += __shfl_xor(part, 4);
  part += __shfl_xor(part, 8);
  float denom = sqrtf(part*(1.f/80.f) + 1e-6f);
  float rinv = 1.f/denom;
  float rln[5];
  #pragma unroll
  for (int i=0;i<5;i++) rln[i] = hv[i]*rinv;

  int g = GRADE16[c];
  #pragma unroll
  for (int o=0;o<10;o++) {
    const float* w1r = w1 + g*50 + o*5;
    float a=0.f;
    #pragma unroll
    for (int i=0;i<5;i++) a += rln[i]*w1r[i];
    sh1[tl][o][c] = a;
  }
  __syncthreads();
  // geometric product: thread c computes gp[hh][c] for all 5 channels
  float gpv[5];
  #pragma unroll
  for (int hh=0; hh<5; hh++) {
    float a = 0.f;
    int n = GPT.cnt[c];
    for (int e=0; e<n; ++e) {
      a += GPT.ss[c][e]*sh1[tl][hh][GPT.ii[c][e]]*sh1[tl][5+hh][GPT.jj[c][e]];
    }
    gpv[hh] = a;
  }
  // gate by gelu(scalar component) -- lane c=0 of this token's 16-lane group
  int base = (tid & 63) & ~15;
  #pragma unroll
  for (int hh=0;hh<5;hh++) {
    float g0 = __shfl(gpv[hh], base);
    float u  = 0.7978845608028654f*(g0 + 0.044715f*g0*g0*g0);
    float gate = 0.5f*g0*(1.f + tanhf(u));
    gpv[hh] *= gate;
  }
  // final equi_linear (w2) + residual
  #pragma unroll
  for (int o=0;o<5;o++) {
    const float* w2r = w2 + g*25 + o*5;
    float a=0.f;
    #pragma unroll
    for (int i=0;i<5;i++) a += gpv[i]*w2r[i];
    ht[o*16+c] += a;
  }
}

// --------------------------------------------------------------------------
// K5: final equi_linear (w_out) + output extraction.
// --------------------------------------------------------------------------
__global__ __launch_bounds__(256) void k_out(
    const float* __restrict__ h, const float* __restrict__ w_out,
    float* __restrict__ out)
{
  int gid = blockIdx.x*256 + threadIdx.x;
  if (gid >= NTOK*35) return;
  int j = gid % 35, token = gid / 35;
  const float* ht = h + (size_t)token*80;
  float a = 0.f;
  if (j < 32) {
    const float* w = w_out + j*5;              // grade 0, row j
    #pragma unroll
    for (int i=0;i<5;i++) a += ht[i*16 + 0]*w[i];
  } else {
    int c = (j==32)?5:((j==33)?6:8);
    const float* w = w_out + 2*160 + 0*5;      // grade 2, row 0
    #pragma unroll
    for (int i=0;i<5;i++) a += ht[i*16 + c]*w[i];
  }
  out[gid] = a;
}

// --------------------------------------------------------------------------
extern "C" void kernel_launch(void* const* d_in, const int* in_sizes, int n_in,
                              void* d_out, int out_size, void* d_ws, size_t ws_size,
                              hipStream_t stream) {
  const float* x     = (const float*)d_in[0];
  const float* w_in  = (const float*)d_in[1];
  const float* w_out = (const float*)d_in[2];
  const float* wq    = (const float*)d_in[3];
  const float* wk    = (const float*)d_in[4];
  const float* wv    = (const float*)d_in[5];
  const float* wo    = (const float*)d_in[6];
  const float* w1    = (const float*)d_in[7];
  const float* w2    = (const float*)d_in[8];
  float* out = (float*)d_out;

  // workspace carve: h fp32 (5.24MB) + qf,kf fp16 [64/row] (2.1MB each) +
  // vf fp16 tiled (2.62MB)  => ~12.1MB total.
  char* p = (char*)d_ws;
  float* h = (float*)p;              p += (size_t)NTOK*80*4;
  _Float16* qf = (_Float16*)p;       p += (size_t)NTOK*QP*2;
  _Float16* kf = (_Float16*)p;       p += (size_t)NTOK*QP*2;
  _Float16* vf = (_Float16*)p;

  k_init_h<<<(NTOK*5 + 255)/256, 256, 0, stream>>>(x, w_in, h);
  for (int blk=0; blk<3; ++blk) {
    k_ln_qkv<<<NTOK/16, 256, 0, stream>>>(h, wq+blk*125, wk+blk*125, wv+blk*125,
                                          qf, kf, vf);
    k_attn_mfma<<<dim3(NSEQ/32, NB), 256, 0, stream>>>(qf, kf, vf,
                                                       wo+blk*125, h);
    k_mlp<<<NTOK/16, 256, 0, stream>>>(h, w1+blk*250, w2+blk*125);
  }
  k_out<<<(NTOK*35 + 255)/256, 256, 0, stream>>>(h, w_out, out);
}